// Round 10
// baseline (124.060 us; speedup 1.0000x reference)
//
#include <hip/hip_runtime.h>

#define LL 8
#define NN 100000
#define HH 128
#define KT 1024
#define BM 32
#define NNHH (NN * HH)

typedef __attribute__((ext_vector_type(4))) float f32x4;
typedef __attribute__((ext_vector_type(8))) short bf16x8;
typedef __attribute__((ext_vector_type(8))) unsigned short u16x8;

__device__ __forceinline__ unsigned short f2bf(float f) {
    unsigned u = __float_as_uint(f);
    unsigned r = ((u >> 16) & 1u) + 0x7fffu;   // RNE
    return (unsigned short)((u + r) >> 16);
}
__device__ __forceinline__ float bf2f(unsigned short s) {
    return __uint_as_float(((unsigned)s) << 16);
}
__device__ __forceinline__ f32x4 ntload4(const float* p) {
    return __builtin_nontemporal_load(reinterpret_cast<const f32x4*>(p));
}

// Pre-pack w_ref (f32 [128 cols][1024 k]) -> bf16 in fragment order:
// wp[(k8*128 + col)*8 + e] = bf16(w_ref[col][k8*8+e]),  k8 = k/8.
__global__ __launch_bounds__(256) void pack_w_kernel(const float* __restrict__ w_ref,
                                                     unsigned short* __restrict__ wp) {
    int gid = blockIdx.x * 256 + threadIdx.x;   // 0..16383
    int col = gid >> 7;
    int k8  = gid & 127;
    const float* s = w_ref + (size_t)col * KT + (size_t)k8 * 8;
    float4 v0 = *reinterpret_cast<const float4*>(s);
    float4 v1 = *reinterpret_cast<const float4*>(s + 4);
    u16x8 p;
    p[0] = f2bf(v0.x); p[1] = f2bf(v0.y); p[2] = f2bf(v0.z); p[3] = f2bf(v0.w);
    p[4] = f2bf(v1.x); p[5] = f2bf(v1.y); p[6] = f2bf(v1.z); p[7] = f2bf(v1.w);
    *reinterpret_cast<u16x8*>(wp + (size_t)(k8 * 128 + col) * 8) = p;
}

// Block = 32 nodes (3125 blocks exact), 512 threads = 8 waves; wave w: 32 nodes
// x cols [w*16,+16). r9 structure (interleaved per-layer pipeline, lgkm-only
// barriers, B register double-buffer, NT loads/stores, layer-resident LDS) with
// ONE change: sx is computed in the EPILOGUE from the bf16 LDS tiles (batched
// butterfly, ILP across layers) instead of per-step serial shfl chains. The
// K-loop's convert phase is now pure {vmcnt-wait, f2bf, ds_write}.
__global__ __launch_bounds__(512, 2)
void gamlp_main(const float* __restrict__ xs,
                const unsigned short* __restrict__ wp,
                const float* __restrict__ b_ref,
                const float* __restrict__ w_att,
                const float* __restrict__ b_att_p,
                const float* __restrict__ alpha_p,
                float* __restrict__ out)
{
    __shared__ unsigned short A_lds[LL][BM * 128];  // 8 x 8KB = 64KB, XOR-swizzled slots
    __shared__ float sjk_lds[BM][8];

    const int tid  = threadIdx.x;
    const int lane = tid & 63;
    const int wave = tid >> 6;      // 0..7
    const int colq = lane & 15;
    const int kq   = lane >> 4;
    const int n0   = blockIdx.x * BM;

    const float alpha = *alpha_p;
    const float batt  = *b_att_p;

    // ---- staging map: thread covers (row = tid>>4 in 0..31, 16B slot = tid&15) ----
    const int slot = tid & 15;
    const int row  = tid >> 4;
    const float* src = xs + (size_t)(n0 + row) * HH + slot * 8;
    const int doff = row * 128 + ((slot ^ (row & 15)) * 8);

    // wa_x slice for this thread's k-slot (f32)
    const f32x4 wax0 = *reinterpret_cast<const f32x4*>(w_att + HH + slot * 8);
    const f32x4 wax1 = *reinterpret_cast<const f32x4*>(w_att + HH + slot * 8 + 4);

    // ---- B fragment pointer (packed bf16, L2-resident); wave covers 16 cols ----
    const unsigned short* pB = wp + (size_t)(wave * 16 + colq) * 8;
    const float wr = w_att[wave * 16 + colq];
    const float br = b_ref[wave * 16 + colq];

    f32x4 acc[2];
    acc[0] = (f32x4){0, 0, 0, 0};
    acc[1] = (f32x4){0, 0, 0, 0};

    f32x4 pf[3][2];

#define LOADS(SET, LAY) do {                                                     \
    const size_t g_ = (size_t)(LAY) * NNHH;                                      \
    pf[SET][0] = ntload4(src + g_);                                              \
    pf[SET][1] = ntload4(src + g_ + 4);                                          \
} while (0)

// pure convert + LDS write: no dot, no shfl, no sx store (hoisted to epilogue)
#define CONVERT_WRITE(SET, LAY) do {                                             \
    u16x8 pk_;                                                                   \
    _Pragma("unroll")                                                            \
    for (int e_ = 0; e_ < 4; e_++) {                                             \
        pk_[e_]   = f2bf(pf[SET][0][e_]);                                        \
        pk_[e_+4] = f2bf(pf[SET][1][e_]);                                        \
    }                                                                            \
    *reinterpret_cast<u16x8*>(&A_lds[LAY][doff]) = pk_;                          \
} while (0)

#define LGKM_BARRIER() do {                                                      \
    asm volatile("s_waitcnt lgkmcnt(0)" ::: "memory");                           \
    __builtin_amdgcn_s_barrier();                                                \
} while (0)

    // ---- B double-buffer: preload step 0's 4 fragments ----
    bf16x8 Bc[4], Bn[4];
    #pragma unroll
    for (int c = 0; c < 4; c++)
        Bc[c] = *reinterpret_cast<const bf16x8*>(pB + (size_t)(c * 4 + kq) * 1024);

    // ---- prologue: 3 layers of loads in flight, convert layer 0 ----
    LOADS(0, 0);
    LOADS(1, 1);
    LOADS(2, 2);
    CONVERT_WRITE(0, 0);
    LGKM_BARRIER();

    // ---- main loop: 8 steps (step == layer), fully unrolled ----
    #pragma unroll
    for (int s = 0; s < 8; s++) {
        if (s + 3 < 8) LOADS((s + 3) % 3, s + 3);
        if (s + 1 < 8) CONVERT_WRITE((s + 1) % 3, s + 1);
        // prefetch next step's B fragments (in flight during MFMAs)
        if (s < 7) {
            const int k8n = (s + 1) * 16;
            #pragma unroll
            for (int c = 0; c < 4; c++)
                Bn[c] = *reinterpret_cast<const bf16x8*>(pB + (size_t)(k8n + c * 4 + kq) * 1024);
        }
        // MFMA on layer s's resident tile
        #pragma unroll
        for (int c = 0; c < 4; c++) {
            bf16x8 af[2];
            #pragma unroll
            for (int m = 0; m < 2; m++) {
                int r = m * 16 + colq;
                af[m] = *reinterpret_cast<const bf16x8*>(
                    &A_lds[s][r * 128 + (((c * 4 + kq) ^ colq) * 8)]);
            }
            acc[0] = __builtin_amdgcn_mfma_f32_16x16x32_bf16(af[0], Bc[c], acc[0], 0, 0, 0);
            acc[1] = __builtin_amdgcn_mfma_f32_16x16x32_bf16(af[1], Bc[c], acc[1], 0, 0, 0);
        }
        #pragma unroll
        for (int c = 0; c < 4; c++) Bc[c] = Bn[c];
        LGKM_BARRIER();
    }

    // ---- sjk: sum over this wave's 16 cols of prelu(jk + b_ref) * wa_ref ----
    // D layout: col = wave*16 + colq, node = m*16 + kq*4 + r
    #pragma unroll
    for (int m = 0; m < 2; m++) {
        float sr[4];
        #pragma unroll
        for (int r = 0; r < 4; r++) {
            float v = acc[m][r] + br;
            v = (v >= 0.f) ? v : alpha * v;
            float sv = v * wr;
            sv += __shfl_xor(sv, 1);
            sv += __shfl_xor(sv, 2);
            sv += __shfl_xor(sv, 4);
            sv += __shfl_xor(sv, 8);
            sr[r] = sv;
        }
        if (colq == 0) {
            #pragma unroll
            for (int r = 0; r < 4; r++)
                sjk_lds[m * 16 + kq * 4 + r][wave] = sr[r];
        }
    }
    __syncthreads();

    // ---- epilogue: sx from LDS bf16 tiles (batched butterfly), softmax,
    //      weighted sum. Thread handles (node = row, slot); xs NOT re-read. ----
    {
        const int node = row;
        const int boff = node * 128 + ((slot ^ (node & 15)) * 8);
        // pass 1: per-layer partial dots (independent -> ILP)
        float sx[LL];
        #pragma unroll
        for (int l = 0; l < LL; l++) {
            u16x8 v = *reinterpret_cast<const u16x8*>(&A_lds[l][boff]);
            float d = 0.f;
            #pragma unroll
            for (int e = 0; e < 4; e++)
                d += bf2f(v[e]) * wax0[e] + bf2f(v[e + 4]) * wax1[e];
            sx[l] = d;
        }
        // batched butterfly over the 16-slot group: 4 levels x 8 layers, ILP 8
        #pragma unroll
        for (int mser = 1; mser <= 8; mser <<= 1) {
            #pragma unroll
            for (int l = 0; l < LL; l++) sx[l] += __shfl_xor(sx[l], mser);
        }
        float sjk = 0.f;
        #pragma unroll
        for (int w8 = 0; w8 < 8; w8++) sjk += sjk_lds[node][w8];
        float sc[LL], mx = 0.f;
        #pragma unroll
        for (int l = 0; l < LL; l++) {
            float sv = sjk + sx[l] + batt;
            sv = fmaxf(sv, 0.f);
            sc[l] = sv;
            mx = fmaxf(mx, sv);
        }
        float den = 0.f;
        #pragma unroll
        for (int l = 0; l < LL; l++) { sc[l] = __expf(sc[l] - mx); den += sc[l]; }
        float inv = 1.f / den;
        // pass 2: weighted sum (re-read LDS; cheap, conflict-pattern unchanged)
        f32x4 o0 = (f32x4){0.f, 0.f, 0.f, 0.f};
        f32x4 o1 = (f32x4){0.f, 0.f, 0.f, 0.f};
        #pragma unroll
        for (int l = 0; l < LL; l++) {
            u16x8 v = *reinterpret_cast<const u16x8*>(&A_lds[l][boff]);
            float wl = sc[l] * inv;
            #pragma unroll
            for (int e = 0; e < 4; e++) {
                o0[e] += wl * bf2f(v[e]);
                o1[e] += wl * bf2f(v[e + 4]);
            }
        }
        float* op = out + (size_t)(n0 + node) * HH + slot * 8;
        __builtin_nontemporal_store(o0, reinterpret_cast<f32x4*>(op));
        __builtin_nontemporal_store(o1, reinterpret_cast<f32x4*>(op + 4));
    }
#undef LOADS
#undef CONVERT_WRITE
#undef LGKM_BARRIER
}

extern "C" void kernel_launch(void* const* d_in, const int* in_sizes, int n_in,
                              void* d_out, int out_size, void* d_ws, size_t ws_size,
                              hipStream_t stream) {
    const float* xs     = (const float*)d_in[0];
    const float* w_ref  = (const float*)d_in[1];
    const float* b_ref  = (const float*)d_in[2];
    const float* w_att  = (const float*)d_in[3];
    const float* b_att  = (const float*)d_in[4];
    const float* alpha  = (const float*)d_in[5];
    float* out = (float*)d_out;
    unsigned short* wp = (unsigned short*)d_ws;   // 256 KB packed bf16 weights

    pack_w_kernel<<<64, 256, 0, stream>>>(w_ref, wp);
    const int grid = NN / BM;                     // 3125, exact
    gamlp_main<<<grid, 512, 0, stream>>>(xs, wp, b_ref, w_att, b_att, alpha, out);
}

// Round 11
// 122.338 us; speedup vs baseline: 1.0141x; 1.0141x over previous
//
#include <hip/hip_runtime.h>

#define LL 8
#define NN 100000
#define HH 128
#define KT 1024
#define BM 32
#define NNHH (NN * HH)

typedef __attribute__((ext_vector_type(4))) float f32x4;
typedef __attribute__((ext_vector_type(8))) short bf16x8;
typedef __attribute__((ext_vector_type(8))) unsigned short u16x8;

__device__ __forceinline__ unsigned short f2bf(float f) {
    unsigned u = __float_as_uint(f);
    unsigned r = ((u >> 16) & 1u) + 0x7fffu;   // RNE
    return (unsigned short)((u + r) >> 16);
}
__device__ __forceinline__ float bf2f(unsigned short s) {
    return __uint_as_float(((unsigned)s) << 16);
}
__device__ __forceinline__ f32x4 ntload4(const float* p) {
    return __builtin_nontemporal_load(reinterpret_cast<const f32x4*>(p));
}

// Pre-pack w_ref (f32 [128 cols][1024 k]) -> bf16 in fragment order:
// wp[(k8*128 + col)*8 + e] = bf16(w_ref[col][k8*8+e]),  k8 = k/8.
__global__ __launch_bounds__(256) void pack_w_kernel(const float* __restrict__ w_ref,
                                                     unsigned short* __restrict__ wp) {
    int gid = blockIdx.x * 256 + threadIdx.x;   // 0..16383
    int col = gid >> 7;
    int k8  = gid & 127;
    const float* s = w_ref + (size_t)col * KT + (size_t)k8 * 8;
    float4 v0 = *reinterpret_cast<const float4*>(s);
    float4 v1 = *reinterpret_cast<const float4*>(s + 4);
    u16x8 p;
    p[0] = f2bf(v0.x); p[1] = f2bf(v0.y); p[2] = f2bf(v0.z); p[3] = f2bf(v0.w);
    p[4] = f2bf(v1.x); p[5] = f2bf(v1.y); p[6] = f2bf(v1.z); p[7] = f2bf(v1.w);
    *reinterpret_cast<u16x8*>(wp + (size_t)(k8 * 128 + col) * 8) = p;
}

// Block = 32 nodes (3125 blocks exact), 512 threads = 8 waves; wave w: 32 nodes
// x cols [w*16,+16). r10 structure (interleaved per-layer pipeline, lgkm-only
// barriers, NT loads/stores, layer-resident LDS, epilogue sx) with pipeline
// fixes against vmcnt issue-order coupling:
//  - B prefetch depth-2, issued FIRST each iteration (before A loads): the
//    MFMA phase's B-wait no longer transitively waits on younger HBM A-loads.
//  - A register pipeline depth 4 (3 steps of latency slack).
__global__ __launch_bounds__(512, 2)
void gamlp_main(const float* __restrict__ xs,
                const unsigned short* __restrict__ wp,
                const float* __restrict__ b_ref,
                const float* __restrict__ w_att,
                const float* __restrict__ b_att_p,
                const float* __restrict__ alpha_p,
                float* __restrict__ out)
{
    __shared__ unsigned short A_lds[LL][BM * 128];  // 8 x 8KB = 64KB, XOR-swizzled slots
    __shared__ float sjk_lds[BM][8];

    const int tid  = threadIdx.x;
    const int lane = tid & 63;
    const int wave = tid >> 6;      // 0..7
    const int colq = lane & 15;
    const int kq   = lane >> 4;
    const int n0   = blockIdx.x * BM;

    const float alpha = *alpha_p;
    const float batt  = *b_att_p;

    // ---- staging map: thread covers (row = tid>>4 in 0..31, 16B slot = tid&15) ----
    const int slot = tid & 15;
    const int row  = tid >> 4;
    const float* src = xs + (size_t)(n0 + row) * HH + slot * 8;
    const int doff = row * 128 + ((slot ^ (row & 15)) * 8);

    // wa_x slice for this thread's k-slot (f32)
    const f32x4 wax0 = *reinterpret_cast<const f32x4*>(w_att + HH + slot * 8);
    const f32x4 wax1 = *reinterpret_cast<const f32x4*>(w_att + HH + slot * 8 + 4);

    // ---- B fragment pointer (packed bf16, L2-resident); wave covers 16 cols ----
    const unsigned short* pB = wp + (size_t)(wave * 16 + colq) * 8;
    const float wr = w_att[wave * 16 + colq];
    const float br = b_ref[wave * 16 + colq];

    f32x4 acc[2];
    acc[0] = (f32x4){0, 0, 0, 0};
    acc[1] = (f32x4){0, 0, 0, 0};

    f32x4 pf[4][2];
    bf16x8 BA[4], BB[4], BC[4];

#define ISSUE_B(DST, STEP) do {                                                  \
    const int k8_ = (STEP) * 16;                                                 \
    _Pragma("unroll")                                                            \
    for (int c_ = 0; c_ < 4; c_++)                                               \
        DST[c_] = *reinterpret_cast<const bf16x8*>(                              \
            pB + (size_t)(k8_ + c_ * 4 + kq) * 1024);                            \
} while (0)

#define LOADS(SET, LAY) do {                                                     \
    const size_t g_ = (size_t)(LAY) * NNHH;                                      \
    pf[SET][0] = ntload4(src + g_);                                              \
    pf[SET][1] = ntload4(src + g_ + 4);                                          \
} while (0)

// pure convert + LDS write: no dot, no shfl (sx lives in the epilogue)
#define CONVERT_WRITE(SET, LAY) do {                                             \
    u16x8 pk_;                                                                   \
    _Pragma("unroll")                                                            \
    for (int e_ = 0; e_ < 4; e_++) {                                             \
        pk_[e_]   = f2bf(pf[SET][0][e_]);                                        \
        pk_[e_+4] = f2bf(pf[SET][1][e_]);                                        \
    }                                                                            \
    *reinterpret_cast<u16x8*>(&A_lds[LAY][doff]) = pk_;                          \
} while (0)

#define LGKM_BARRIER() do {                                                      \
    asm volatile("s_waitcnt lgkmcnt(0)" ::: "memory");                           \
    __builtin_amdgcn_s_barrier();                                                \
} while (0)

    // ---- prologue: B(0),B(1) issued BEFORE the A stream; 4 A-layers in flight ----
    ISSUE_B(BA, 0);
    ISSUE_B(BB, 1);
    LOADS(0, 0);
    LOADS(1, 1);
    LOADS(2, 2);
    LOADS(3, 3);
    CONVERT_WRITE(0, 0);
    LGKM_BARRIER();

    // ---- main loop: 8 steps (step == layer), fully unrolled ----
    #pragma unroll
    for (int s = 0; s < 8; s++) {
        // (0) B prefetch FIRST: depth-2, decoupled from the A HBM stream
        if (s + 2 < 8) ISSUE_B(BC, s + 2);
        // (1) A loads: depth-4 register pipeline
        if (s + 4 < 8) LOADS((s + 4) & 3, s + 4);
        // (2) convert + ds_write next layer (vmcnt-waits A(s+1), issued 3 steps ago)
        if (s + 1 < 8) CONVERT_WRITE((s + 1) & 3, s + 1);
        // (3) MFMA on layer s's resident tile with BA = B(s) (issued 2 steps ago)
        #pragma unroll
        for (int c = 0; c < 4; c++) {
            bf16x8 af[2];
            #pragma unroll
            for (int m = 0; m < 2; m++) {
                int r = m * 16 + colq;
                af[m] = *reinterpret_cast<const bf16x8*>(
                    &A_lds[s][r * 128 + (((c * 4 + kq) ^ colq) * 8)]);
            }
            acc[0] = __builtin_amdgcn_mfma_f32_16x16x32_bf16(af[0], BA[c], acc[0], 0, 0, 0);
            acc[1] = __builtin_amdgcn_mfma_f32_16x16x32_bf16(af[1], BA[c], acc[1], 0, 0, 0);
        }
        // (4) shift B pipeline
        #pragma unroll
        for (int c = 0; c < 4; c++) { BA[c] = BB[c]; BB[c] = BC[c]; }
        LGKM_BARRIER();
    }

    // ---- sjk: sum over this wave's 16 cols of prelu(jk + b_ref) * wa_ref ----
    // D layout: col = wave*16 + colq, node = m*16 + kq*4 + r
    #pragma unroll
    for (int m = 0; m < 2; m++) {
        float sr[4];
        #pragma unroll
        for (int r = 0; r < 4; r++) {
            float v = acc[m][r] + br;
            v = (v >= 0.f) ? v : alpha * v;
            float sv = v * wr;
            sv += __shfl_xor(sv, 1);
            sv += __shfl_xor(sv, 2);
            sv += __shfl_xor(sv, 4);
            sv += __shfl_xor(sv, 8);
            sr[r] = sv;
        }
        if (colq == 0) {
            #pragma unroll
            for (int r = 0; r < 4; r++)
                sjk_lds[m * 16 + kq * 4 + r][wave] = sr[r];
        }
    }
    __syncthreads();

    // ---- epilogue: sx from LDS bf16 tiles (batched butterfly), softmax,
    //      weighted sum. Thread handles (node = row, slot); xs NOT re-read. ----
    {
        const int node = row;
        const int boff = node * 128 + ((slot ^ (node & 15)) * 8);
        // pass 1: per-layer partial dots (independent -> ILP)
        float sx[LL];
        #pragma unroll
        for (int l = 0; l < LL; l++) {
            u16x8 v = *reinterpret_cast<const u16x8*>(&A_lds[l][boff]);
            float d = 0.f;
            #pragma unroll
            for (int e = 0; e < 4; e++)
                d += bf2f(v[e]) * wax0[e] + bf2f(v[e + 4]) * wax1[e];
            sx[l] = d;
        }
        // batched butterfly over the 16-slot group: 4 levels x 8 layers, ILP 8
        #pragma unroll
        for (int mser = 1; mser <= 8; mser <<= 1) {
            #pragma unroll
            for (int l = 0; l < LL; l++) sx[l] += __shfl_xor(sx[l], mser);
        }
        float sjk = 0.f;
        #pragma unroll
        for (int w8 = 0; w8 < 8; w8++) sjk += sjk_lds[node][w8];
        float sc[LL], mx = 0.f;
        #pragma unroll
        for (int l = 0; l < LL; l++) {
            float sv = sjk + sx[l] + batt;
            sv = fmaxf(sv, 0.f);
            sc[l] = sv;
            mx = fmaxf(mx, sv);
        }
        float den = 0.f;
        #pragma unroll
        for (int l = 0; l < LL; l++) { sc[l] = __expf(sc[l] - mx); den += sc[l]; }
        float inv = 1.f / den;
        // pass 2: weighted sum (re-read LDS; conflict-pattern unchanged)
        f32x4 o0 = (f32x4){0.f, 0.f, 0.f, 0.f};
        f32x4 o1 = (f32x4){0.f, 0.f, 0.f, 0.f};
        #pragma unroll
        for (int l = 0; l < LL; l++) {
            u16x8 v = *reinterpret_cast<const u16x8*>(&A_lds[l][boff]);
            float wl = sc[l] * inv;
            #pragma unroll
            for (int e = 0; e < 4; e++) {
                o0[e] += wl * bf2f(v[e]);
                o1[e] += wl * bf2f(v[e + 4]);
            }
        }
        float* op = out + (size_t)(n0 + node) * HH + slot * 8;
        __builtin_nontemporal_store(o0, reinterpret_cast<f32x4*>(op));
        __builtin_nontemporal_store(o1, reinterpret_cast<f32x4*>(op + 4));
    }
#undef ISSUE_B
#undef LOADS
#undef CONVERT_WRITE
#undef LGKM_BARRIER
}

extern "C" void kernel_launch(void* const* d_in, const int* in_sizes, int n_in,
                              void* d_out, int out_size, void* d_ws, size_t ws_size,
                              hipStream_t stream) {
    const float* xs     = (const float*)d_in[0];
    const float* w_ref  = (const float*)d_in[1];
    const float* b_ref  = (const float*)d_in[2];
    const float* w_att  = (const float*)d_in[3];
    const float* b_att  = (const float*)d_in[4];
    const float* alpha  = (const float*)d_in[5];
    float* out = (float*)d_out;
    unsigned short* wp = (unsigned short*)d_ws;   // 256 KB packed bf16 weights

    pack_w_kernel<<<64, 256, 0, stream>>>(w_ref, wp);
    const int grid = NN / BM;                     // 3125, exact
    gamlp_main<<<grid, 512, 0, stream>>>(xs, wp, b_ref, w_att, b_att, alpha, out);
}